// Round 1
// 99.675 us; speedup vs baseline: 1.0023x; 1.0023x over previous
//
#include <hip/hip_runtime.h>

// Round 7: dual-tile PC loop (one lever vs R6).
// Theory: with 1 block/CU (128 KB LDS) and 2 waves/SIMD, run_strip's
// per-tile chain QK(2 dep MFMA) -> exp2 -> pack -> PV is latency-exposed:
// each solo key tile carries ~200 cycles of dependency that 2 waves cannot
// fill. R7 processes two key tiles per iteration with source-interleaved
// QK/exp so tile B's MFMAs fill tile A's exp-chain stalls. Pairing (w,15-w)
// keeps every wave at exactly 7 dual + 1 solo + 2 diag iterations.
// K prefetch sits between pack and PV so ds_read latency hides under the
// 16 PV MFMAs; prefetch address is clamped (branchless) to keep the dual
// body a single straight-line scheduling region.

#define SEQ 512
#define CH  64

#define SLOT_STRIDE 72                    // padded Q-transpose slot row (shorts)
#define SLOT_SIZE   (32 * SLOT_STRIDE)    // 2304 shorts per wave
#define WOFF        (8 * SLOT_SIZE)       // weight frag images at ldsK + 18432

typedef __attribute__((ext_vector_type(8))) short bf16x8;
typedef __attribute__((ext_vector_type(4))) short bf16x4;
typedef __attribute__((ext_vector_type(4))) float f32x4;

static __device__ __forceinline__ short f2bf(float f) {
  union { float f; unsigned u; } v; v.f = f;
  unsigned r = v.u + 0x7FFFu + ((v.u >> 16) & 1u);   // RNE
  return (short)(r >> 16);
}

static __device__ __forceinline__ bf16x4 pack4(f32x4 v) {
  bf16x4 r;
  r[0] = f2bf(v[0]); r[1] = f2bf(v[1]); r[2] = f2bf(v[2]); r[3] = f2bf(v[3]);
  return r;
}

static __device__ __forceinline__ f32x4 mfma32(bf16x8 a, bf16x8 b, f32x4 c) {
  return __builtin_amdgcn_mfma_f32_16x16x32_bf16(a, b, c, 0, 0, 0);
}

// pack two f32 -> bf16x2 dword by truncation (1 VALU)
static __device__ __forceinline__ unsigned pperm(float hi, float lo) {
#if defined(__has_builtin) && __has_builtin(__builtin_amdgcn_perm)
  return __builtin_amdgcn_perm(__builtin_bit_cast(unsigned, hi),
                               __builtin_bit_cast(unsigned, lo), 0x07060302u);
#else
  return (__builtin_bit_cast(unsigned, hi) & 0xFFFF0000u) |
         (__builtin_bit_cast(unsigned, lo) >> 16);
#endif
}

#if defined(__has_builtin) && __has_builtin(__builtin_amdgcn_exp2f)
#define EXP2(v) __builtin_amdgcn_exp2f(v)
#else
#define EXP2(v) __expf((v) * 0.6931471805599453f)
#endif

static __device__ __forceinline__ void wave_lds_fence() {
  asm volatile("s_waitcnt lgkmcnt(0)" ::: "memory");
}

// Q fragments for one 32-row strip via the wave-private padded slot.
static __device__ __forceinline__ void make_qf(
    const float* __restrict__ xb, const bf16x8 WQf[4][2],
    unsigned short* slot, int q0, int l15, int quad, bf16x8 qf[2][2]) {
#pragma unroll
  for (int nn = 0; nn < 2; ++nn) {
    bf16x8 xa[2];
#pragma unroll
    for (int c = 0; c < 2; ++c) {
      const float* px = xb + (size_t)(q0 + nn * 16 + l15) * CH + c * 32 + quad * 8;
      float4 lo = *(const float4*)px;
      float4 hi = *(const float4*)(px + 4);
      bf16x8 f;
      f[0] = f2bf(lo.x); f[1] = f2bf(lo.y); f[2] = f2bf(lo.z); f[3] = f2bf(lo.w);
      f[4] = f2bf(hi.x); f[5] = f2bf(hi.y); f[6] = f2bf(hi.z); f[7] = f2bf(hi.w);
      xa[c] = f;
    }
#pragma unroll
    for (int cht = 0; cht < 4; ++cht) {
      f32x4 qt = {0.f, 0.f, 0.f, 0.f};
#pragma unroll
      for (int c = 0; c < 2; ++c)
        qt = mfma32(WQf[cht][c], xa[c], qt);   // Q^T[16cht+4q+r][q0+16nn+l15]
      *(bf16x4*)(slot + (nn * 16 + l15) * SLOT_STRIDE + cht * 16 + quad * 4) = pack4(qt);
    }
  }
  wave_lds_fence();
#pragma unroll
  for (int nn = 0; nn < 2; ++nn)
#pragma unroll
    for (int c = 0; c < 2; ++c)
      qf[nn][c] = *(const bf16x8*)(slot + (nn * 16 + l15) * SLOT_STRIDE + c * 32 + quad * 8);
  wave_lds_fence();   // drain reads before slot is overwritten
}

static __device__ __forceinline__ void load_kv4(bf16x8 d[4],
                                                const unsigned short* p, int lane) {
#pragma unroll
  for (int i = 0; i < 4; ++i)
    d[i] = *(const bf16x8*)(p + i * 512 + lane * 8);
}

// One full (non-diagonal) key tile.
static __device__ __forceinline__ void tile_full(
    const bf16x8 kf[4], const bf16x8 vf[4], const bf16x8 qf[2][2],
    f32x4 ot[2][4], float& ls0, float& ls1) {
  f32x4 st00 = {0.f,0.f,0.f,0.f}, st01 = {0.f,0.f,0.f,0.f};
  f32x4 st10 = {0.f,0.f,0.f,0.f}, st11 = {0.f,0.f,0.f,0.f};
  st00 = mfma32(kf[0], qf[0][0], st00); st00 = mfma32(kf[1], qf[0][1], st00);
  st01 = mfma32(kf[0], qf[1][0], st01); st01 = mfma32(kf[1], qf[1][1], st01);
  st10 = mfma32(kf[2], qf[0][0], st10); st10 = mfma32(kf[3], qf[0][1], st10);
  st11 = mfma32(kf[2], qf[1][0], st11); st11 = mfma32(kf[3], qf[1][1], st11);
  union { bf16x8 v; unsigned u[4]; } P0, P1;
#pragma unroll
  for (int r = 0; r < 4; ++r) {
    st00[r] = EXP2(st00[r]);  ls0 += st00[r];
    st10[r] = EXP2(st10[r]);  ls0 += st10[r];
    st01[r] = EXP2(st01[r]);  ls1 += st01[r];
    st11[r] = EXP2(st11[r]);  ls1 += st11[r];
  }
  P0.u[0] = pperm(st00[1], st00[0]); P0.u[1] = pperm(st00[3], st00[2]);
  P0.u[2] = pperm(st10[1], st10[0]); P0.u[3] = pperm(st10[3], st10[2]);
  P1.u[0] = pperm(st01[1], st01[0]); P1.u[1] = pperm(st01[3], st01[2]);
  P1.u[2] = pperm(st11[1], st11[0]); P1.u[3] = pperm(st11[3], st11[2]);
  ot[0][0] = mfma32(vf[0], P0.v, ot[0][0]);  ot[1][0] = mfma32(vf[0], P1.v, ot[1][0]);
  ot[0][1] = mfma32(vf[1], P0.v, ot[0][1]);  ot[1][1] = mfma32(vf[1], P1.v, ot[1][1]);
  ot[0][2] = mfma32(vf[2], P0.v, ot[0][2]);  ot[1][2] = mfma32(vf[2], P1.v, ot[1][2]);
  ot[0][3] = mfma32(vf[3], P0.v, ot[0][3]);  ot[1][3] = mfma32(vf[3], P1.v, ot[1][3]);
}

// Diagonal tile (causal mask).
static __device__ __forceinline__ void diag_tile(
    const bf16x8 kf[4], const unsigned short* vp, const bf16x8 qf[2][2],
    f32x4 ot[2][4], float& ls0, float& ls1, int lane, int dthr) {
  bf16x8 vf[4];
  load_kv4(vf, vp, lane);
  f32x4 st00 = {0.f,0.f,0.f,0.f}, st01 = {0.f,0.f,0.f,0.f}, st11 = {0.f,0.f,0.f,0.f};
  st00 = mfma32(kf[0], qf[0][0], st00); st00 = mfma32(kf[1], qf[0][1], st00);
  st01 = mfma32(kf[0], qf[1][0], st01); st01 = mfma32(kf[1], qf[1][1], st01);
  st11 = mfma32(kf[2], qf[1][0], st11); st11 = mfma32(kf[3], qf[1][1], st11);
  union { bf16x8 v; unsigned u[4]; } P0, P1;
#pragma unroll
  for (int r = 0; r < 4; ++r) {
    st00[r] = (r > dthr) ? 0.f : EXP2(st00[r]);  ls0 += st00[r];
    st11[r] = (r > dthr) ? 0.f : EXP2(st11[r]);  ls1 += st11[r];
    st01[r] = EXP2(st01[r]);                     ls1 += st01[r];
  }
  P0.u[0] = pperm(st00[1], st00[0]); P0.u[1] = pperm(st00[3], st00[2]);
  P0.u[2] = 0u;                      P0.u[3] = 0u;   // keys 16-31 masked for cols 0-15
  P1.u[0] = pperm(st01[1], st01[0]); P1.u[1] = pperm(st01[3], st01[2]);
  P1.u[2] = pperm(st11[1], st11[0]); P1.u[3] = pperm(st11[3], st11[2]);
  ot[0][0] = mfma32(vf[0], P0.v, ot[0][0]);  ot[1][0] = mfma32(vf[0], P1.v, ot[1][0]);
  ot[0][1] = mfma32(vf[1], P0.v, ot[0][1]);  ot[1][1] = mfma32(vf[1], P1.v, ot[1][1]);
  ot[0][2] = mfma32(vf[2], P0.v, ot[0][2]);  ot[1][2] = mfma32(vf[2], P1.v, ot[1][2]);
  ot[0][3] = mfma32(vf[3], P0.v, ot[0][3]);  ot[1][3] = mfma32(vf[3], P1.v, ot[1][3]);
}

// One 32-query strip: dual-tile key loop + solo/diag tail + epilogue.
static __device__ __forceinline__ void run_strip(
    int s, const bf16x8 qf[2][2], const unsigned short* __restrict__ ldsK,
    const unsigned short* __restrict__ ldsV, float* __restrict__ outb,
    int lane, int l15, int quad) {
  const int q0 = s * 32;
  f32x4 ot[2][4];
#pragma unroll
  for (int nn = 0; nn < 2; ++nn)
#pragma unroll
    for (int cht = 0; cht < 4; ++cht) ot[nn][cht] = (f32x4){0.f, 0.f, 0.f, 0.f};
  float ls0 = 0.f, ls1 = 0.f;
  const int dthr = l15 - quad * 4;

  // invariant at loop head: kf0 = K[t], kf1 = K[t+1] (when t+1 <= s)
  bf16x8 kf0[4], kf1[4];
  load_kv4(kf0, ldsK, lane);
  if (s >= 1) load_kv4(kf1, ldsK + 2048, lane);

  int t = 0;
#pragma unroll 1
  while (t + 1 < s) {            // tiles t and t+1 both non-diagonal
    bf16x8 vf0[4], vf1[4];
    load_kv4(vf0, ldsV + t * 2048, lane);
    load_kv4(vf1, ldsV + (t + 1) * 2048, lane);

    // ---- QK for both tiles, source-interleaved (independent chains)
    f32x4 a00 = {0.f,0.f,0.f,0.f}, a01 = {0.f,0.f,0.f,0.f};
    f32x4 a10 = {0.f,0.f,0.f,0.f}, a11 = {0.f,0.f,0.f,0.f};
    f32x4 b00 = {0.f,0.f,0.f,0.f}, b01 = {0.f,0.f,0.f,0.f};
    f32x4 b10 = {0.f,0.f,0.f,0.f}, b11 = {0.f,0.f,0.f,0.f};
    a00 = mfma32(kf0[0], qf[0][0], a00); a00 = mfma32(kf0[1], qf[0][1], a00);
    b00 = mfma32(kf1[0], qf[0][0], b00); b00 = mfma32(kf1[1], qf[0][1], b00);
    a01 = mfma32(kf0[0], qf[1][0], a01); a01 = mfma32(kf0[1], qf[1][1], a01);
    b01 = mfma32(kf1[0], qf[1][0], b01); b01 = mfma32(kf1[1], qf[1][1], b01);
    a10 = mfma32(kf0[2], qf[0][0], a10); a10 = mfma32(kf0[3], qf[0][1], a10);
    b10 = mfma32(kf1[2], qf[0][0], b10); b10 = mfma32(kf1[3], qf[0][1], b10);
    a11 = mfma32(kf0[2], qf[1][0], a11); a11 = mfma32(kf0[3], qf[1][1], a11);
    b11 = mfma32(kf1[2], qf[1][0], b11); b11 = mfma32(kf1[3], qf[1][1], b11);

    // ---- exp2 + row sums, both tiles interleaved
#pragma unroll
    for (int r = 0; r < 4; ++r) {
      a00[r] = EXP2(a00[r]);  ls0 += a00[r];
      a10[r] = EXP2(a10[r]);  ls0 += a10[r];
      a01[r] = EXP2(a01[r]);  ls1 += a01[r];
      a11[r] = EXP2(a11[r]);  ls1 += a11[r];
      b00[r] = EXP2(b00[r]);  ls0 += b00[r];
      b10[r] = EXP2(b10[r]);  ls0 += b10[r];
      b01[r] = EXP2(b01[r]);  ls1 += b01[r];
      b11[r] = EXP2(b11[r]);  ls1 += b11[r];
    }

    union { bf16x8 v; unsigned u[4]; } PA0, PA1, PB0, PB1;
    PA0.u[0] = pperm(a00[1], a00[0]); PA0.u[1] = pperm(a00[3], a00[2]);
    PA0.u[2] = pperm(a10[1], a10[0]); PA0.u[3] = pperm(a10[3], a10[2]);
    PA1.u[0] = pperm(a01[1], a01[0]); PA1.u[1] = pperm(a01[3], a01[2]);
    PA1.u[2] = pperm(a11[1], a11[0]); PA1.u[3] = pperm(a11[3], a11[2]);
    PB0.u[0] = pperm(b00[1], b00[0]); PB0.u[1] = pperm(b00[3], b00[2]);
    PB0.u[2] = pperm(b10[1], b10[0]); PB0.u[3] = pperm(b10[3], b10[2]);
    PB1.u[0] = pperm(b01[1], b01[0]); PB1.u[1] = pperm(b01[3], b01[2]);
    PB1.u[2] = pperm(b11[1], b11[0]); PB1.u[3] = pperm(b11[3], b11[2]);

    // ---- K prefetch for next pair: kf0/kf1 free after QK; ds_read latency
    //      hides under the 16 PV MFMAs below. Clamp keeps this branchless.
    load_kv4(kf0, ldsK + (t + 2) * 2048, lane);        // t+2 <= s guaranteed
    {
      const int tn = (t + 3 <= s) ? (t + 3) : s;
      load_kv4(kf1, ldsK + tn * 2048, lane);
    }

    // ---- PV: tile A then tile B (acc chains pipelined)
    ot[0][0] = mfma32(vf0[0], PA0.v, ot[0][0]);  ot[1][0] = mfma32(vf0[0], PA1.v, ot[1][0]);
    ot[0][1] = mfma32(vf0[1], PA0.v, ot[0][1]);  ot[1][1] = mfma32(vf0[1], PA1.v, ot[1][1]);
    ot[0][2] = mfma32(vf0[2], PA0.v, ot[0][2]);  ot[1][2] = mfma32(vf0[2], PA1.v, ot[1][2]);
    ot[0][3] = mfma32(vf0[3], PA0.v, ot[0][3]);  ot[1][3] = mfma32(vf0[3], PA1.v, ot[1][3]);
    ot[0][0] = mfma32(vf1[0], PB0.v, ot[0][0]);  ot[1][0] = mfma32(vf1[0], PB1.v, ot[1][0]);
    ot[0][1] = mfma32(vf1[1], PB0.v, ot[0][1]);  ot[1][1] = mfma32(vf1[1], PB1.v, ot[1][1]);
    ot[0][2] = mfma32(vf1[2], PB0.v, ot[0][2]);  ot[1][2] = mfma32(vf1[2], PB1.v, ot[1][2]);
    ot[0][3] = mfma32(vf1[3], PB0.v, ot[0][3]);  ot[1][3] = mfma32(vf1[3], PB1.v, ot[1][3]);

    t += 2;
  }

  if (t < s) {                   // t == s-1: one leftover non-diag tile
    bf16x8 vfs[4];
    load_kv4(vfs, ldsV + t * 2048, lane);
    tile_full(kf0, vfs, qf, ot, ls0, ls1);
    diag_tile(kf1, ldsV + (size_t)s * 2048, qf, ot, ls0, ls1, lane, dthr);
  } else {                       // t == s
    diag_tile(kf0, ldsV + (size_t)s * 2048, qf, ot, ls0, ls1, lane, dthr);
  }

  // column sums live across the 4 quads
  ls0 += __shfl_xor(ls0, 16); ls0 += __shfl_xor(ls0, 32);
  ls1 += __shfl_xor(ls1, 16); ls1 += __shfl_xor(ls1, 32);
  const float inv0 = 1.0f / ls0, inv1 = 1.0f / ls1;

#pragma unroll
  for (int nn = 0; nn < 2; ++nn) {
    const float inv = nn ? inv1 : inv0;
#pragma unroll
    for (int cht = 0; cht < 4; ++cht) {
      float4 v;
      v.x = ot[nn][cht][0] * inv; v.y = ot[nn][cht][1] * inv;
      v.z = ot[nn][cht][2] * inv; v.w = ot[nn][cht][3] * inv;
      *(float4*)(outb + (size_t)(q0 + nn * 16 + l15) * CH + cht * 16 + quad * 4) = v;
    }
  }
}

__global__ __launch_bounds__(512, 2)
void attn_fused(const float* __restrict__ x,
                const float* __restrict__ wk,
                const float* __restrict__ wq,
                const float* __restrict__ wv,
                float* __restrict__ out) {
  // ldsK: finally the K frag image (64 KB); before that, overlaid:
  //   [0, 18432)        8 wave-private padded Q-transpose slots (36 KB)
  //   [18432, 30720)    24 weight frag images, 512 shorts each (24 KB)
  // ldsV: V frag image (64 KB), written in phase B only.
  __shared__ alignas(16) unsigned short ldsK[SEQ * CH];
  __shared__ alignas(16) unsigned short ldsV[SEQ * CH];

  const int b    = blockIdx.x;
  const int w    = threadIdx.x >> 6;   // wave 0..7
  const int lane = threadIdx.x & 63;
  const int l15  = lane & 15;
  const int quad = lane >> 4;

  const float* xb   = x + (size_t)b * SEQ * CH;
  float*       outb = out + (size_t)b * SEQ * CH;

  // ---- P0: cooperative weight frag-image build (wave w -> chunk w of each matrix)
  {
    const int t = w >> 1, c = w & 1;
    const int k0 = c * 32 + quad * 8;
    const int n  = t * 16 + l15;
#pragma unroll
    for (int m = 0; m < 3; ++m) {
      const float* Wsrc  = (m == 0) ? wq : (m == 1) ? wk : wv;
      const float  scale = (m == 0) ? 0.18033688011112042f : 1.0f;  // C^-0.5*log2e
      bf16x8 fr;
#pragma unroll
      for (int j = 0; j < 8; ++j)
        fr[j] = f2bf(Wsrc[(k0 + j) * CH + n] * scale);
      *(bf16x8*)(ldsK + WOFF + (m * 8 + w) * 512 + lane * 8) = fr;
    }
  }
  __syncthreads();

  // ---- PA: Q fragments for strips {w, 15-w}
  const int sA = w, sB = 15 - w;
  unsigned short* slot = ldsK + w * SLOT_SIZE;
  bf16x8 qfA[2][2], qfB[2][2];
  {
    bf16x8 WQf[4][2];
#pragma unroll
    for (int t = 0; t < 4; ++t)
#pragma unroll
      for (int c = 0; c < 2; ++c)
        WQf[t][c] = *(const bf16x8*)(ldsK + WOFF + (t * 2 + c) * 512 + lane * 8);
    make_qf(xb, WQf, slot, sA * 32, l15, quad, qfA);
    make_qf(xb, WQf, slot, sB * 32, l15, quad, qfB);
  }

  // ---- PB: K,V frag images; wave w projects tokens [64w, 64w+64)
  {
    bf16x8 WKf[4][2], WVf[4][2];
#pragma unroll
    for (int t = 0; t < 4; ++t)
#pragma unroll
      for (int c = 0; c < 2; ++c) {
        WKf[t][c] = *(const bf16x8*)(ldsK + WOFF + (8  + t * 2 + c) * 512 + lane * 8);
        WVf[t][c] = *(const bf16x8*)(ldsK + WOFF + (16 + t * 2 + c) * 512 + lane * 8);
      }
    __syncthreads();   // slots + weight area free before K image overwrites them

#pragma unroll
    for (int sub = 0; sub < 4; ++sub) {
      const int t16 = w * 64 + sub * 16;
      bf16x8 xa[2];
#pragma unroll
      for (int c = 0; c < 2; ++c) {
        const float* px = xb + (size_t)(t16 + l15) * CH + c * 32 + quad * 8;
        float4 lo = *(const float4*)px;
        float4 hi = *(const float4*)(px + 4);
        bf16x8 f;
        f[0] = f2bf(lo.x); f[1] = f2bf(lo.y); f[2] = f2bf(lo.z); f[3] = f2bf(lo.w);
        f[4] = f2bf(hi.x); f[5] = f2bf(hi.y); f[6] = f2bf(hi.z); f[7] = f2bf(hi.w);
        xa[c] = f;
      }
#pragma unroll
      for (int cht = 0; cht < 4; ++cht) {   // K^T C-frags -> frag-image store
        f32x4 ak = {0.f, 0.f, 0.f, 0.f};
#pragma unroll
        for (int c = 0; c < 2; ++c)
          ak = mfma32(WKf[cht][c], xa[c], ak);
        const int cdst = cht >> 1;
        const int qp   = ((cht & 1) << 1) | (quad >> 1);
        *(bf16x4*)(ldsK + (t16 >> 4) * 1024 + cdst * 512 +
                   (qp * 16 + l15) * 8 + (quad & 1) * 4) = pack4(ak);
      }
#pragma unroll
      for (int nt = 0; nt < 4; ++nt) {      // V C-frags -> key-permuted V^T image
        f32x4 av = {0.f, 0.f, 0.f, 0.f};
#pragma unroll
        for (int c = 0; c < 2; ++c)
          av = mfma32(xa[c], WVf[nt][c], av);
        *(bf16x4*)(ldsV + (t16 >> 5) * 2048 + nt * 512 +
                   (quad * 16 + l15) * 8 + ((t16 >> 4) & 1) * 4) = pack4(av);
      }
    }
  }
  __syncthreads();

  // ---- PC: two balanced strips, 7 dual + 1 solo + 2 diag iterations per wave
  run_strip(sA, qfA, ldsK, ldsV, outb, lane, l15, quad);
  run_strip(sB, qfB, ldsK, ldsV, outb, lane, l15, quad);
}

extern "C" void kernel_launch(void* const* d_in, const int* in_sizes, int n_in,
                              void* d_out, int out_size, void* d_ws, size_t ws_size,
                              hipStream_t stream) {
  const float* x  = (const float*)d_in[0];
  const float* wk = (const float*)d_in[1];   // w_key
  const float* wq = (const float*)d_in[2];   // w_query
  const float* wv = (const float*)d_in[3];   // w_value
  (void)in_sizes; (void)n_in; (void)out_size; (void)d_ws; (void)ws_size;
  attn_fused<<<256, 512, 0, stream>>>(x, wk, wq, wv, (float*)d_out);
}